// Round 1
// 142.017 us; speedup vs baseline: 1.1858x; 1.1858x over previous
//
#include <hip/hip_runtime.h>
#include <hip/hip_bf16.h>

// RecursiveNN, perfect binary tree. N=262144 leaves, IN=64, HID=128.
// SETTLED: inputs fp32 jax-layout ([K,N] weights), output fp32[128].
// R8: 174.6us. R10: 168.4us (pair-column frags, kfront stops at M=4).
// R11 (this): kprep prestages bf16 B-frags (tanh 2/ln2 scale folded into W,b)
//   into d_ws (80KB, slot-major coalesced); kfront/kmid/ktail load frags as
//   coalesced dwordx4 instead of 80 scattered float2 + ~240 cvt per thread;
//   bias moved into MFMA acc init; tanh drops mul+add (exp2/rcp/fma only).
//   kmid/ktail lose stage_w_t + 69KB Wt LDS.
//
// In-place in leaf_x buffer XB:
//  kprep  5 blocks: W frags -> d_ws.
//  kfront b: leaf GEMM + levels 1..5 on 128 leaves -> 4 fp32 rows at
//            XB[8192b + {0..3}*128] (own consumed region).
//  kmid t (64 blocks): gather 128 rows from kfront blocks 32t..32t+31,
//            levels 6..12 -> 1 row at XB[262144t + 512].
//  ktail: 64 rows -> levels 13..18 -> root fp32[128] -> d_out.
// H LDS: row stride 136 bf16, col swizzle c ^ (((row>>3)&3)<<3).

typedef unsigned short u16;
typedef unsigned int u32;
typedef __attribute__((ext_vector_type(8))) short bf16x8;   // 8 bf16, 4 VGPR
typedef __attribute__((ext_vector_type(4))) float f32x4;

#define TANH_S 2.8853900817779268f  // 2/ln2; tanh(x) = 1 - 2/(exp2(S*x)+1)

__device__ __forceinline__ u16 f2bf(float f) {
    __hip_bfloat16 h = __float2bfloat16(f);   // RNE
    return *(u16*)&h;
}
// packed RNE cvt: lo16 = bf16(a), hi16 = bf16(b)
__device__ __forceinline__ u32 f2bf_pk(float a, float b) {
    __hip_bfloat162 h = __float22bfloat162_rn(make_float2(a, b));
    return *(u32*)&h;
}
// NaN-free tanh, input PRE-SCALED by TANH_S (scale folded into weights/bias)
__device__ __forceinline__ float tanh_ps(float xs) {
#if __has_builtin(__builtin_amdgcn_exp2f) && __has_builtin(__builtin_amdgcn_rcpf)
    float t = __builtin_amdgcn_exp2f(xs);
    float r = __builtin_amdgcn_rcpf(t + 1.0f);
    return __builtin_fmaf(-2.0f, r, 1.0f);
#else
    float e = __expf(xs * 0.6931471805599453f);
    return 1.0f - 2.0f / (e + 1.0f);
#endif
}
__device__ __forceinline__ int swz(int row, int c) {
    return c ^ (((row >> 3) & 3) << 3);
}

#define MFMA16(a, b, c) __builtin_amdgcn_mfma_f32_16x16x32_bf16((a), (b), (c), 0, 0, 0)

// ---- d_ws frag layout (u16 units) ------------------------------------------
// bw   slot s = kc*2+i (16 slots): ws[s*2048 + tid*8]  -> 65536 B
// bwin slot s = kc*2+i ( 4 slots): ws[32768 + s*2048 + tid*8] -> 16384 B
// Per-instruction: 64 lanes x 16B contiguous => fully coalesced dwordx4.
#define WS_BWIN 32768
#define WS_BYTES 81920

// ---- kprep: materialize bf16 B-frags (scaled by TANH_S) into d_ws ----------
__global__ __launch_bounds__(256) void kprep(
    const float* __restrict__ Win, const float* __restrict__ Wl,
    const float* __restrict__ Wr, u16* __restrict__ ws) {
    const int tid = threadIdx.x;
    const int w = tid >> 6, lane = tid & 63, quad = lane >> 4, lq = lane & 15;
    const int c0 = 32 * w + 2 * lq;
    const int part = blockIdx.x;             // 0..3: bw kc-pairs; 4: bwin
    if (part < 4) {
#pragma unroll
        for (int kk = 0; kk < 2; ++kk) {
            const int kc = part * 2 + kk;
            const float* W = (kc < 4) ? Wl : Wr;
            const int kbase = (kc & 3) * 32 + quad * 8;
            bf16x8 f0, f1;
#pragma unroll
            for (int j = 0; j < 8; ++j) {
                float2 v = *(const float2*)(W + (size_t)(kbase + j) * 128 + c0);
                f0[j] = (short)f2bf(v.x * TANH_S);
                f1[j] = (short)f2bf(v.y * TANH_S);
            }
            *(bf16x8*)(ws + (kc * 2 + 0) * 2048 + tid * 8) = f0;
            *(bf16x8*)(ws + (kc * 2 + 1) * 2048 + tid * 8) = f1;
        }
    } else {
#pragma unroll
        for (int kc = 0; kc < 2; ++kc) {
            const int kbase = kc * 32 + quad * 8;
            bf16x8 f0, f1;
#pragma unroll
            for (int j = 0; j < 8; ++j) {
                float2 v = *(const float2*)(Win + (size_t)(kbase + j) * 128 + c0);
                f0[j] = (short)f2bf(v.x * TANH_S);
                f1[j] = (short)f2bf(v.y * TANH_S);
            }
            *(bf16x8*)(ws + WS_BWIN + (kc * 2 + 0) * 2048 + tid * 8) = f0;
            *(bf16x8*)(ws + WS_BWIN + (kc * 2 + 1) * 2048 + tid * 8) = f1;
        }
    }
}

// ---- coalesced frag loads from d_ws ----------------------------------------
__device__ __forceinline__ void load_bw_ws(const u16* __restrict__ ws, int tid,
                                           bf16x8 (&bw)[8][2]) {
#pragma unroll
    for (int kc = 0; kc < 8; ++kc) {
        bw[kc][0] = *(const bf16x8*)(ws + (kc * 2 + 0) * 2048 + tid * 8);
        bw[kc][1] = *(const bf16x8*)(ws + (kc * 2 + 1) * 2048 + tid * 8);
    }
}

// ---- pairwise levels: Mfirst..Mlast; at M==Mlast write fp32 rows to out ----
// Bias is carried in the accumulator init; tanh input is pre-scaled.
__device__ __forceinline__ void run_levels_mfma(
    u16* b0, u16* b1, int Mfirst, int Mlast, const bf16x8 (&bw)[8][2],
    float bs0, float bs1, float* finalOut, int quad, int lq, int c0) {
    u16* in = b0;
    u16* out = b1;
    for (int M = Mfirst; M >= Mlast; M >>= 1) {
        const int ntiles = (M + 15) >> 4;
        for (int rt = 0; rt < ntiles; ++rt) {
            const int r0e = rt * 16;
            bf16x8 a[8];
#pragma unroll
            for (int kc = 0; kc < 8; ++kc) {
                const int row = 2 * (r0e + lq) + (kc >> 2);
                const int kb = (kc & 3) * 32 + quad * 8;
                a[kc] = *(const bf16x8*)(in + row * 136 + swz(row, kb));
            }
            f32x4 ac0 = {bs0, bs0, bs0, bs0}, ac1 = {bs1, bs1, bs1, bs1};
#pragma unroll
            for (int kc = 0; kc < 8; ++kc) {
                ac0 = MFMA16(a[kc], bw[kc][0], ac0);
                ac1 = MFMA16(a[kc], bw[kc][1], ac1);
            }
#pragma unroll
            for (int r = 0; r < 4; ++r) {
                const int ro = r0e + quad * 4 + r;
                if (ro < M) {
                    float v0 = tanh_ps(ac0[r]);
                    float v1 = tanh_ps(ac1[r]);
                    if (M == Mlast) {
                        *(float2*)(finalOut + ro * 128 + c0) = make_float2(v0, v1);
                    } else {
                        *(u32*)(out + ro * 136 + swz(ro, c0)) = f2bf_pk(v0, v1);
                    }
                }
            }
        }
        __syncthreads();
        u16* t = in; in = out; out = t;
    }
}

// ---- kfront: leaf GEMM + levels 1..5 for a 128-leaf subtree ----------------
__global__ __launch_bounds__(256, 2) void kfront(
    float* XB, const float* __restrict__ bin,
    const float* __restrict__ bl, const float* __restrict__ br,
    const u16* __restrict__ ws) {
    __shared__ __align__(16) u16 H0[128 * 136];   // 34816 B
    __shared__ __align__(16) u16 POOL[128 * 72];  // 18432 B: Xa, then H1
    // 53248 B total; VGPR ~112 (no spill)

    const int tid = threadIdx.x;
    const int w = tid >> 6, lane = tid & 63, quad = lane >> 4, lq = lane & 15;
    const int b = blockIdx.x;
    const int c0 = 32 * w + 2 * lq;               // pair (c0, c0+1)
    u16* Xa = POOL;   // [128][72] bf16 leaf inputs
    u16* H1 = POOL;   // [64][136] after leaf phase (Xa dead)

    const float* Xg = XB + (size_t)b * 8192;      // 128 rows x 64
#pragma unroll
    for (int t = 0; t < 8; ++t) {
        int i4 = tid + 256 * t;
        int r = i4 >> 4, k4 = (i4 & 15) << 2;
        float4 v = *(const float4*)(Xg + r * 64 + k4);
        *(uint2*)(Xa + r * 72 + k4) =
            make_uint2(f2bf_pk(v.x, v.y), f2bf_pk(v.z, v.w));
    }

    // coalesced prestaged frags (scattered loads + cvt eliminated)
    bf16x8 bwin[2][2];
#pragma unroll
    for (int kc = 0; kc < 2; ++kc) {
        bwin[kc][0] = *(const bf16x8*)(ws + WS_BWIN + (kc * 2 + 0) * 2048 + tid * 8);
        bwin[kc][1] = *(const bf16x8*)(ws + WS_BWIN + (kc * 2 + 1) * 2048 + tid * 8);
    }
    bf16x8 bw[8][2];
    load_bw_ws(ws, tid, bw);

    const float2 binp = *(const float2*)(bin + c0);
    const float2 blp = *(const float2*)(bl + c0);
    const float2 brp = *(const float2*)(br + c0);
    const float bi0 = binp.x * TANH_S, bi1 = binp.y * TANH_S;
    const float bs0 = (blp.x + brp.x) * TANH_S, bs1 = (blp.y + brp.y) * TANH_S;
    __syncthreads();

    // leaf GEMM: [128x64] @ [64x128], 8 row-tiles, K=64 = 2 MFMA per acc
    for (int rt = 0; rt < 8; ++rt) {
        const int r0e = rt * 16;
        const int rowa = r0e + lq;
        bf16x8 a0 = *(const bf16x8*)(Xa + rowa * 72 + quad * 8);
        bf16x8 a1 = *(const bf16x8*)(Xa + rowa * 72 + 32 + quad * 8);
        f32x4 ac0 = {bi0, bi0, bi0, bi0}, ac1 = {bi1, bi1, bi1, bi1};
        ac0 = MFMA16(a0, bwin[0][0], ac0);
        ac0 = MFMA16(a1, bwin[1][0], ac0);
        ac1 = MFMA16(a0, bwin[0][1], ac1);
        ac1 = MFMA16(a1, bwin[1][1], ac1);
#pragma unroll
        for (int r = 0; r < 4; ++r) {
            const int ro = r0e + quad * 4 + r;
            *(u32*)(H0 + ro * 136 + swz(ro, c0)) =
                f2bf_pk(tanh_ps(ac0[r]), tanh_ps(ac1[r]));
        }
    }
    __syncthreads();   // H0 complete; Xa reads done (H1 aliases Xa)

    // levels 1..5 (M=64..4); write 4 fp32 rows into own region
    run_levels_mfma(H0, H1, 64, 4, bw, bs0, bs1, XB + (size_t)b * 8192,
                    quad, lq, c0);
}

// ---- kmid: 64 blocks, gather 128 rows, levels 6..12 -> 1 row ---------------
__global__ __launch_bounds__(256) void kmid(
    float* XB, const float* __restrict__ bl, const float* __restrict__ br,
    const u16* __restrict__ ws) {
    __shared__ __align__(16) u16 H0[128 * 136];
    __shared__ __align__(16) u16 H1[64 * 136];    // 52224 B total (Wt gone)

    const int tid = threadIdx.x;
    const int w = tid >> 6, lane = tid & 63, quad = lane >> 4, lq = lane & 15;
    const int t = blockIdx.x;
    const int c0 = 32 * w + 2 * lq;

    bf16x8 bw[8][2];
    load_bw_ws(ws, tid, bw);                      // issue early, hide latency

    // 128 rows: kfront block 32t+(r>>2), sub-row r&3
#pragma unroll
    for (int it = 0; it < 16; ++it) {
        int i4 = tid + 256 * it;
        int r = i4 >> 5, k4 = (i4 & 31) << 2;
        const float* src = XB + (size_t)8192 * (32 * t + (r >> 2)) + (r & 3) * 128 + k4;
        float4 v = *(const float4*)src;
        *(uint2*)(H0 + r * 136 + swz(r, k4)) =
            make_uint2(f2bf_pk(v.x, v.y), f2bf_pk(v.z, v.w));
    }
    const float2 blp = *(const float2*)(bl + c0);
    const float2 brp = *(const float2*)(br + c0);
    const float bs0 = (blp.x + brp.x) * TANH_S, bs1 = (blp.y + brp.y) * TANH_S;
    __syncthreads();

    run_levels_mfma(H0, H1, 64, 1, bw, bs0, bs1,
                    XB + (size_t)262144 * t + 512, quad, lq, c0);
}

// ---- ktail: 64 rows -> levels 13..18 -> root fp32 --------------------------
__global__ __launch_bounds__(256) void ktail(
    const float* XB, const float* __restrict__ bl, const float* __restrict__ br,
    const u16* __restrict__ ws, float* __restrict__ out) {
    __shared__ __align__(16) u16 H0[64 * 136];
    __shared__ __align__(16) u16 H1[64 * 136];    // 34816 B total

    const int tid = threadIdx.x;
    const int w = tid >> 6, lane = tid & 63, quad = lane >> 4, lq = lane & 15;
    const int c0 = 32 * w + 2 * lq;

    bf16x8 bw[8][2];
    load_bw_ws(ws, tid, bw);

    // 64 rows from XB[262144*r + 512]
#pragma unroll
    for (int it = 0; it < 8; ++it) {
        int i4 = tid + 256 * it;
        int r = i4 >> 5, k4 = (i4 & 31) << 2;     // r = 0..63
        float4 v = *(const float4*)(XB + (size_t)262144 * r + 512 + k4);
        *(uint2*)(H0 + r * 136 + swz(r, k4)) =
            make_uint2(f2bf_pk(v.x, v.y), f2bf_pk(v.z, v.w));
    }
    const float2 blp = *(const float2*)(bl + c0);
    const float2 brp = *(const float2*)(br + c0);
    const float bs0 = (blp.x + brp.x) * TANH_S, bs1 = (blp.y + brp.y) * TANH_S;
    __syncthreads();

    run_levels_mfma(H0, H1, 32, 1, bw, bs0, bs1, out, quad, lq, c0);
}

// ---- host ------------------------------------------------------------------
extern "C" void kernel_launch(void* const* d_in, const int* in_sizes, int n_in,
                              void* d_out, int out_size, void* d_ws, size_t ws_size,
                              hipStream_t stream) {
    float* XB = (float*)d_in[0];              // consumed then reused in-place
    const float* Win = (const float*)d_in[1];
    const float* bin = (const float*)d_in[2];
    const float* Wl  = (const float*)d_in[3];
    const float* bl  = (const float*)d_in[4];
    const float* Wr  = (const float*)d_in[5];
    const float* br  = (const float*)d_in[6];
    float* out = (float*)d_out;
    u16* ws = (u16*)d_ws;                     // needs WS_BYTES = 81920 B

    kprep<<<5, 256, 0, stream>>>(Win, Wl, Wr, ws);
    kfront<<<2048, 256, 0, stream>>>(XB, bin, bl, br, ws);
    kmid<<<64, 256, 0, stream>>>(XB, bl, br, ws);
    ktail<<<1, 256, 0, stream>>>(XB, bl, br, ws, out);
}